// Round 11
// baseline (594.372 us; speedup 1.0000x reference)
//
#include <hip/hip_runtime.h>

#define NPTS 8192
#define NSQ ((size_t)NPTS * (size_t)NPTS)
#define JPT 16   // j-points per thread (was 8): halves total wave count

__device__ __forceinline__ float bf16_to_f(unsigned short u) {
    return __uint_as_float(((unsigned int)u) << 16);
}
__device__ __forceinline__ unsigned short f_to_bf16_rne(float f) {
    unsigned int x = __float_as_uint(f);
    x += 0x7FFFu + ((x >> 16) & 1u);
    return (unsigned short)(x >> 16);
}

// R11 = R9/R10 body with DOUBLE the work per thread (JPT 8->16).
// Evidence: R9 (32768 blk x 256thr) and R10 (8192 blk x 1024thr) are within
// 8us of each other -- block count/size is NOT the bottleneck. Both run the
// SAME 131072 waves; kernel ~165us vs ~43us write floor and ~27us VALU =>
// ~20% issue utilization => per-WAVE fixed cost (probe, row-load latency,
// end-of-wave drain) is the remaining suspect. This round halves wave count
// to 65536 and doubles per-wave store width (32B/plane/thread).
// Launch geometry: grid.y = 8192 (one block per output row) kept -- shared
// by both passing runs; R2-R8's grid.y=1024 all failed (nothing-written).
// grid.x/block-size proven free by R10.
//
// Dtype detected IN-KERNEL per wave (probe v1, identical to R0/R9/R10 which
// pass): read pos's first 64 u16s as bf16; true bf16 coords lie in [0,16];
// f32 low mantissa halves decode to wild exponents. __all() -> wave-uniform.
// Output dtype couples to input dtype (as in all passing runs).
//
// Numerics replicate the np reference order exactly per (i,j) (absmax 2^-8):
//   sq  = ((x*x)+(y*y))+(z*z)
//   dot = fma(z,z', fma(y,y', x*x'))   ascending-k accumulation
//   d   = (sq_i + sq_j) - 2*dot ; max(d,0) ; mask = d <= 1
__global__ __launch_bounds__(512) void radius_kernel(
    const void* __restrict__ pos_raw,
    void* __restrict__ out_raw) {

    const int i  = blockIdx.y;
    const int j0 = (int)threadIdx.x * JPT;   // 512 threads x 16 = 8192 cols

    // ---- wave-uniform dtype probe (v1, verbatim) ----
    const unsigned short* pu = (const unsigned short*)pos_raw;
    const float probe = bf16_to_f(pu[threadIdx.x & 63]);
    const bool lane_ok = (probe >= 0.0f) && (probe <= 16.0f);  // NaN fails
    const bool is_f32 = !__all(lane_ok);

    float flat[3 * JPT];   // x0 y0 z0 ... for the 16 j-points
    float xi, yi, zi;

    if (is_f32) {
        const float* pos = (const float*)pos_raw;
        const float4* p4 = (const float4*)(pos + (size_t)j0 * 3); // 192B, 16B-aligned
#pragma unroll
        for (int q = 0; q < 12; ++q) ((float4*)flat)[q] = p4[q];
        xi = pos[i * 3 + 0]; yi = pos[i * 3 + 1]; zi = pos[i * 3 + 2];
    } else {
        const unsigned short* pos = (const unsigned short*)pos_raw;
        unsigned short us[3 * JPT];
        const uint4* p4 = (const uint4*)(pos + (size_t)j0 * 3);   // 96B, 16B-aligned
#pragma unroll
        for (int q = 0; q < 6; ++q) ((uint4*)us)[q] = p4[q];
#pragma unroll
        for (int t = 0; t < 3 * JPT; ++t) flat[t] = bf16_to_f(us[t]);
        xi = bf16_to_f(pos[i * 3 + 0]);
        yi = bf16_to_f(pos[i * 3 + 1]);
        zi = bf16_to_f(pos[i * 3 + 2]);
    }

    const float sqi = __fadd_rn(__fadd_rn(__fmul_rn(xi, xi), __fmul_rn(yi, yi)),
                                __fmul_rn(zi, zi));

    float dval[JPT];
    bool  mval[JPT];
#pragma unroll
    for (int t = 0; t < JPT; ++t) {
        const float x = flat[3 * t + 0];
        const float y = flat[3 * t + 1];
        const float z = flat[3 * t + 2];
        const float sqj = __fadd_rn(
            __fadd_rn(__fmul_rn(x, x), __fmul_rn(y, y)), __fmul_rn(z, z));
        const float dot = __fmaf_rn(zi, z, __fmaf_rn(yi, y, __fmul_rn(xi, x)));
        float d = __fsub_rn(__fadd_rn(sqi, sqj), __fmul_rn(2.0f, dot));
        d = fmaxf(d, 0.0f);
        const bool m = (d <= 1.0f);
        dval[t] = m ? d : 0.0f;
        mval[t] = m;
    }

    const size_t off = (size_t)i * NPTS + (size_t)j0;

    if (is_f32) {
        float* out_md   = (float*)out_raw;
        float* out_mask = out_md + NSQ;
        float md8[JPT], mk8[JPT];
#pragma unroll
        for (int t = 0; t < JPT; ++t) { md8[t] = dval[t]; mk8[t] = mval[t] ? 1.0f : 0.0f; }
#pragma unroll
        for (int q = 0; q < JPT / 4; ++q) {
            ((float4*)(out_md + off))[q]   = ((float4*)md8)[q];
            ((float4*)(out_mask + off))[q] = ((float4*)mk8)[q];
        }
    } else {
        unsigned short* out_md   = (unsigned short*)out_raw;
        unsigned short* out_mask = out_md + NSQ;
        unsigned short md8[JPT], mk8[JPT];
#pragma unroll
        for (int t = 0; t < JPT; ++t) {
            md8[t] = f_to_bf16_rne(dval[t]);
            mk8[t] = mval[t] ? (unsigned short)0x3F80u : (unsigned short)0u;
        }
#pragma unroll
        for (int q = 0; q < JPT / 8; ++q) {
            ((uint4*)(out_md + off))[q]   = ((uint4*)md8)[q];
            ((uint4*)(out_mask + off))[q] = ((uint4*)mk8)[q];
        }
    }
}

extern "C" void kernel_launch(void* const* d_in, const int* in_sizes, int n_in,
                              void* d_out, int out_size, void* d_ws, size_t ws_size,
                              hipStream_t stream) {
    (void)in_sizes; (void)n_in; (void)out_size; (void)d_ws; (void)ws_size;

    dim3 block(512, 1, 1);
    dim3 grid(1, NPTS, 1);  // one block per output row; grid.y = 8192 preserved
    radius_kernel<<<grid, block, 0, stream>>>(d_in[0], d_out);
}

// Round 12
// 514.113 us; speedup vs baseline: 1.1561x; 1.1561x over previous
//
#include <hip/hip_runtime.h>

#define NPTS 8192
#define NSQ ((size_t)NPTS * (size_t)NPTS)

__device__ __forceinline__ float bf16_to_f(unsigned short u) {
    return __uint_as_float(((unsigned int)u) << 16);
}
__device__ __forceinline__ unsigned short f_to_bf16_rne(float f) {
    unsigned int x = __float_as_uint(f);
    x += 0x7FFFu + ((x >> 16) & 1u);
    return (unsigned short)(x >> 16);
}
// LDS XOR-swizzle: breaks the stride-48B 8-way bank conflict down to 2-way
// (free, m136) while keeping 16B alignment (only flips bits 4-5).
__device__ __forceinline__ unsigned int swz(unsigned int a) {
    return a ^ (((a >> 7) & 3u) << 4);
}

// R12: R9's kernel at R9's EXACT launch geometry (4,8192)x256 -- the twice-
// proven passing config -- with ONE in-body change on the bf16 path:
// the j-slab is staged through LDS so global reads are coalesced.
//
// EVIDENCE (R9/R10/R11): block count 4x (R10) -> +8us; wave count 0.5x but
// transaction density 2x worse (R11) -> +80us. Bottleneck = memory
// TRANSACTION throughput. R9's stores are already full-line-optimal; its
// j-slab reads are lane-stride 48B (each uint4 load instr scatters over ~48
// cachelines -> ~48 L1 replays x 3 instrs x 131072 waves). This round:
//   stage:  thread t global-loads chunks {t, t+256, t+512} (16B/lane
//           CONTIGUOUS) -> LDS at swizzled addresses (<=2-way conflicts)
//   read:   3x ds_read_b128 at swz(t*48 + q*16): stride-48 would be 8-way
//           (lanes t,t+8 share a bank); swizzle makes it exactly 2-way=free.
// f32 path: R9 verbatim (never observed in 7 runs; keep risk surface small).
//
// GEOMETRY LAW (R2-R8 vs R0/R9/R10): grid.y=8192 (one block-row per output
// row) is load-bearing for this harness; grid.y=1024 fails with a nothing-
// written signature. grid.x/block-size/body are free (R10/R11 passed).
//
// Dtype probe v1 (all passing runs): read pos's first 64 u16s as bf16; true
// bf16 coords lie in [0,16]; f32 low mantissa halves decode to wild
// exponents. __all() -> wave-uniform verdict. Out dtype = in dtype.
//
// Numerics: np reference order exactly (for bf16 inputs all f32 ops here are
// EXACT, so order is provably irrelevant; kept identical anyway):
//   sq  = ((x*x)+(y*y))+(z*z)
//   dot = fma(z,z', fma(y,y', x*x'))
//   d   = (sq_i + sq_j) - 2*dot ; max(d,0) ; mask = d <= 1
__global__ __launch_bounds__(256) void radius_kernel(
    const void* __restrict__ pos_raw,
    void* __restrict__ out_raw) {

    const int i  = blockIdx.y;
    const int j0 = blockIdx.x * 2048 + (int)threadIdx.x * 8;

    __shared__ unsigned char lds_raw[12288];  // 2048 pts x 6B bf16, swizzled

    // ---- wave-uniform dtype probe (v1, verbatim) ----
    const unsigned short* pu = (const unsigned short*)pos_raw;
    const float probe = bf16_to_f(pu[threadIdx.x & 63]);
    const bool lane_ok = (probe >= 0.0f) && (probe <= 16.0f);  // NaN fails
    const bool is_f32 = !__all(lane_ok);

    float flat[24];  // x0 y0 z0 ... x7 y7 z7 for the 8 j-points
    float xi, yi, zi;

    if (is_f32) {
        const float* pos = (const float*)pos_raw;
        const float4* p4 = (const float4*)(pos + (size_t)j0 * 3); // 96B, 16B-aligned
#pragma unroll
        for (int q = 0; q < 6; ++q) ((float4*)flat)[q] = p4[q];
        xi = pos[i * 3 + 0]; yi = pos[i * 3 + 1]; zi = pos[i * 3 + 2];
    } else {
        const unsigned short* pos = (const unsigned short*)pos_raw;

        // ---- coalesced LDS staging of this block's 2048-point slab ----
        // slab base: blockIdx.x * 2048 points * 6 B = blockIdx.x * 12288 B
        const uint4* slab = (const uint4*)(pos + (size_t)blockIdx.x * 2048 * 3);
        const unsigned int t = threadIdx.x;
#pragma unroll
        for (int q = 0; q < 3; ++q) {
            const unsigned int c = t + (unsigned int)q * 256u;   // chunk id
            const uint4 v = slab[c];                              // 16B/lane contiguous
            *(uint4*)&lds_raw[swz(c * 16u)] = v;
        }
        __syncthreads();

        unsigned short us[24];
#pragma unroll
        for (int q = 0; q < 3; ++q) {
            const uint4 v = *(const uint4*)&lds_raw[swz(t * 48u + (unsigned int)q * 16u)];
            ((uint4*)us)[q] = v;
        }
#pragma unroll
        for (int k = 0; k < 24; ++k) flat[k] = bf16_to_f(us[k]);

        xi = bf16_to_f(pos[i * 3 + 0]);
        yi = bf16_to_f(pos[i * 3 + 1]);
        zi = bf16_to_f(pos[i * 3 + 2]);
    }

    const float sqi = __fadd_rn(__fadd_rn(__fmul_rn(xi, xi), __fmul_rn(yi, yi)),
                                __fmul_rn(zi, zi));

    float dval[8];
    bool  mval[8];
#pragma unroll
    for (int t = 0; t < 8; ++t) {
        const float x = flat[3 * t + 0];
        const float y = flat[3 * t + 1];
        const float z = flat[3 * t + 2];
        const float sqj = __fadd_rn(
            __fadd_rn(__fmul_rn(x, x), __fmul_rn(y, y)), __fmul_rn(z, z));
        const float dot = __fmaf_rn(zi, z, __fmaf_rn(yi, y, __fmul_rn(xi, x)));
        float d = __fsub_rn(__fadd_rn(sqi, sqj), __fmul_rn(2.0f, dot));
        d = fmaxf(d, 0.0f);
        const bool m = (d <= 1.0f);
        dval[t] = m ? d : 0.0f;
        mval[t] = m;
    }

    const size_t off = (size_t)i * NPTS + (size_t)j0;

    if (is_f32) {
        float* out_md   = (float*)out_raw;
        float* out_mask = out_md + NSQ;
        float md8[8], mk8[8];
#pragma unroll
        for (int t = 0; t < 8; ++t) { md8[t] = dval[t]; mk8[t] = mval[t] ? 1.0f : 0.0f; }
        ((float4*)(out_md + off))[0]   = ((float4*)md8)[0];
        ((float4*)(out_md + off))[1]   = ((float4*)md8)[1];
        ((float4*)(out_mask + off))[0] = ((float4*)mk8)[0];
        ((float4*)(out_mask + off))[1] = ((float4*)mk8)[1];
    } else {
        unsigned short* out_md   = (unsigned short*)out_raw;
        unsigned short* out_mask = out_md + NSQ;
        unsigned short md8[8], mk8[8];
#pragma unroll
        for (int t = 0; t < 8; ++t) {
            md8[t] = f_to_bf16_rne(dval[t]);
            mk8[t] = mval[t] ? (unsigned short)0x3F80u : (unsigned short)0u;
        }
        *(uint4*)(out_md + off)   = *(uint4*)md8;
        *(uint4*)(out_mask + off) = *(uint4*)mk8;
    }
}

extern "C" void kernel_launch(void* const* d_in, const int* in_sizes, int n_in,
                              void* d_out, int out_size, void* d_ws, size_t ws_size,
                              hipStream_t stream) {
    (void)in_sizes; (void)n_in; (void)out_size; (void)d_ws; (void)ws_size;

    dim3 block(256, 1, 1);
    dim3 grid(NPTS / 2048, NPTS, 1);  // (4, 8192) -- the proven geometry
    radius_kernel<<<grid, block, 0, stream>>>(d_in[0], d_out);
}